// Round 6
// baseline (252.470 us; speedup 1.0000x reference)
//
#include <hip/hip_runtime.h>
#include <hip/hip_fp16.h>
#include <stdint.h>

typedef int i32x4 __attribute__((ext_vector_type(4)));

#define BM 256
#define BN 256
#define BKB 64            // K-bytes (= int8 elems) per tile
#define NSLOT 3
#define SLOT_BYTES 32768  // A 16KB + B 16KB per slot
#define THREADS 256

__device__ __forceinline__ void gload_lds16(const void* g, void* l) {
  __builtin_amdgcn_global_load_lds(
      (const __attribute__((address_space(1))) unsigned int*)g,
      (__attribute__((address_space(3))) unsigned int*)l, 16, 0, 0);
}

// ---------------- quantize x: fp32(fp16 values) -> int8, grid-stride --------
__global__ __launch_bounds__(256) void quant_x_kernel(
    const float* __restrict__ x, const float* __restrict__ deltap,
    const float* __restrict__ zpp, int8_t* __restrict__ q, int n16) {
  const float rdelta = 1.0f / deltap[0];
  const float zp = zpp[0];
  for (int i = blockIdx.x * blockDim.x + threadIdx.x; i < n16;
       i += gridDim.x * blockDim.x) {
    const float4* src = (const float4*)x + (size_t)i * 4;
    int packed[4];
#pragma unroll
    for (int g = 0; g < 4; ++g) {
      float4 v = src[g];
      float f0 = fminf(127.f, fmaxf(-128.f, rintf(fmaf(v.x, rdelta, zp))));
      float f1 = fminf(127.f, fmaxf(-128.f, rintf(fmaf(v.y, rdelta, zp))));
      float f2 = fminf(127.f, fmaxf(-128.f, rintf(fmaf(v.z, rdelta, zp))));
      float f3 = fminf(127.f, fmaxf(-128.f, rintf(fmaf(v.w, rdelta, zp))));
      int q0 = (int)f0 & 255, q1 = (int)f1 & 255, q2 = (int)f2 & 255, q3 = (int)f3 & 255;
      packed[g] = q0 | (q1 << 8) | (q2 << 16) | (q3 << 24);
    }
    ((int4*)q)[i] = make_int4(packed[0], packed[1], packed[2], packed[3]);
  }
}

// ---------------- pack W: int32 -> int8, 16 elems/thread --------------------
__global__ __launch_bounds__(256) void pack_w_kernel(
    const int* __restrict__ w, int8_t* __restrict__ wp, int n16) {
  int i = blockIdx.x * blockDim.x + threadIdx.x;
  if (i >= n16) return;
  const int4* src = (const int4*)w + (size_t)i * 4;
  int packed[4];
#pragma unroll
  for (int g = 0; g < 4; ++g) {
    int4 v = src[g];
    packed[g] = (v.x & 255) | ((v.y & 255) << 8) | ((v.z & 255) << 16) | ((v.w & 255) << 24);
  }
  ((int4*)wp)[i] = make_int4(packed[0], packed[1], packed[2], packed[3]);
}

// ---------------- int8 GEMM, 256x256 tile, 4 waves of 128x128 ---------------
// Max ops/LDS-byte: per-wave 128x128 out -> 16 ds_read_b128 per wave per
// K-tile for 2.1M ops (2x round-5's density). acc[8][8] i32x4 = 256 VGPR,
// 1 wave/SIMD. LDS: 3-slot rotation (96KB), depth-2 prefetch, 8 gloads/stage,
// steady vmcnt(8). One barrier per K-tile; compiler-scheduled interior.
// T2 chunk swizzle (0 conflicts, verified r2-r5) + T1 XCD swizzle.
__global__ __launch_bounds__(THREADS, 1) void gemm_i8_kernel(
    const int8_t* __restrict__ Aq, const int8_t* __restrict__ Bw,
    const float* __restrict__ atwd, const float* __restrict__ zpws,
    const float* __restrict__ bias, float* __restrict__ out,
    int Mc, int Nc, int Kc) {
  __shared__ int8_t lds[NSLOT * SLOT_BYTES];

  // ---- T1 bijective XCD swizzle (nwg multiple of 8 here) ----
  const int nwg = gridDim.x;
  int bid = blockIdx.x;
  if ((nwg & 7) == 0) bid = (bid & 7) * (nwg >> 3) + (bid >> 3);
  const int nbn = Nc / BN;
  const int bm = bid / nbn;
  const int bn = bid % nbn;

  const int tid = threadIdx.x;
  const size_t K = (size_t)Kc;
  const int NT = Kc / BKB;

  // ---- staging: sweep = 256 thr x 16B = 4KB = 64 rows x 64B ----
  const int srow = tid >> 2;                        // 0..63
  const int lc = (tid & 3) ^ ((tid >> 3) & 3);      // inverse-swizzled chunk
  const int8_t* gA = Aq + ((size_t)(bm * BM + srow)) * K + lc * 16;
  const int8_t* gB = Bw + ((size_t)(bn * BN + srow)) * K + lc * 16;
  const size_t row64 = (size_t)64 * K;
  int8_t* ldst = &lds[tid * 16];

  auto stage = [&](int t, int slot) {   // 8 gloads: A 4x4KB, B 4x4KB
    int8_t* l = ldst + slot * SLOT_BYTES;
    const size_t koff = (size_t)t * BKB;
#pragma unroll
    for (int r = 0; r < 4; ++r)
      gload_lds16(gA + koff + r * row64, l + r * 4096);
#pragma unroll
    for (int r = 0; r < 4; ++r)
      gload_lds16(gB + koff + r * row64, l + 16384 + r * 4096);
  };

  // ---- fragment geometry: 4 waves, 2x2, each 128x128 ----
  const int lane = tid & 63;
  const int wave = tid >> 6;
  const int wr = wave >> 1;          // 0..1 -> 128 rows
  const int wc = wave & 1;           // 0..1 -> 128 cols
  const int fr = lane & 15;
  const int kc = lane >> 4;
  const int coff = ((kc ^ ((fr >> 1) & 3)) << 4);  // swizzled ds_read chunk
  const int aRow = wr * 128 + fr;
  const int bRow = wc * 128 + fr;

  i32x4 acc[8][8] = {};

  // ---- prologue: stage U(0),U(1); drain U(0) (keep U(1)'s 8 in flight) ----
  stage(0, 0);
  if (NT > 1) stage(1, 1);
  if (NT > 1) asm volatile("s_waitcnt vmcnt(8)" ::: "memory");
  else        asm volatile("s_waitcnt vmcnt(0)" ::: "memory");
  __builtin_amdgcn_s_barrier();
  __builtin_amdgcn_sched_barrier(0);

  int rs = 0;  // read slot for tile t
  for (int t = 0; t < NT; ++t) {
    const int8_t* sA = &lds[rs * SLOT_BYTES];
    const int8_t* sB = sA + 16384;

    i32x4 afr[8], bfr[8];
#pragma unroll
    for (int j = 0; j < 8; ++j)
      bfr[j] = *(const i32x4*)&sB[(bRow + j * 16) * 64 + coff];
#pragma unroll
    for (int i = 0; i < 8; ++i)
      afr[i] = *(const i32x4*)&sA[(aRow + i * 16) * 64 + coff];

    if (t + 2 < NT) {
      int ws = rs + 2; if (ws >= NSLOT) ws -= NSLOT;
      stage(t + 2, ws);
    }

#pragma unroll
    for (int i = 0; i < 8; ++i)
#pragma unroll
      for (int j = 0; j < 8; ++j)
        acc[i][j] = __builtin_amdgcn_mfma_i32_16x16x64_i8(afr[i], bfr[j], acc[i][j], 0, 0, 0);

    // ---- tile boundary: counted wait (U(t+1) landed), collective barrier ----
    if (t < NT - 1) {
      if (t + 2 < NT) asm volatile("s_waitcnt vmcnt(8)" ::: "memory");
      else            asm volatile("s_waitcnt vmcnt(0)" ::: "memory");
      __builtin_amdgcn_s_barrier();
      __builtin_amdgcn_sched_barrier(0);
    }
    rs = rs + 1; if (rs >= NSLOT) rs -= NSLOT;
  }

  // ---- epilogue: C/D layout col=lane&15, row=(lane>>4)*4+reg.
  // j innermost: 8x16 lanes cover 128 consecutive floats of one row.
  const int r4 = (lane >> 4) << 2;
  const int cn0 = bn * BN + wc * 128 + fr;
  float aw8[8], zs8[8], bs8[8];
#pragma unroll
  for (int j = 0; j < 8; ++j) {
    aw8[j] = atwd[cn0 + j * 16];
    zs8[j] = zpws[cn0 + j * 16];
    bs8[j] = bias[cn0 + j * 16];
  }
#pragma unroll
  for (int mi = 0; mi < 8; ++mi) {
#pragma unroll
    for (int r = 0; r < 4; ++r) {
      const size_t rbase = (size_t)(bm * BM + wr * 128 + mi * 16 + r4 + r) * (size_t)Nc;
#pragma unroll
      for (int j = 0; j < 8; ++j) {
        float v = (float)acc[mi][j][r] * aw8[j] - zs8[j] + bs8[j];
        v = __half2float(__float2half(v));  // match fp16 output rounding
        out[rbase + cn0 + j * 16] = v;
      }
    }
  }
}

extern "C" void kernel_launch(void* const* d_in, const int* in_sizes, int n_in,
                              void* d_out, int out_size, void* d_ws, size_t ws_size,
                              hipStream_t stream) {
  const float* x         = (const float*)d_in[0];
  const float* act_delta = (const float*)d_in[1];
  const float* act_zp    = (const float*)d_in[2];
  const float* zpws      = (const float*)d_in[3];
  const float* atwd      = (const float*)d_in[4];
  const float* bias      = (const float*)d_in[5];
  const int*   w32       = (const int*)d_in[6];
  float* out = (float*)d_out;

  const int N = in_sizes[5];
  const int K = in_sizes[6] / N;
  const int M = in_sizes[0] / K;

  int8_t* q  = (int8_t*)d_ws;               // M*K bytes
  int8_t* wp = q + (size_t)M * K;           // N*K bytes

  {
    int n16 = (M * K) / 16;
    int grid = (n16 + 255) / 256;
    if (grid > 2048) grid = 2048;
    quant_x_kernel<<<grid, 256, 0, stream>>>(x, act_delta, act_zp, q, n16);
  }
  {
    int n16 = (N * K) / 16;
    pack_w_kernel<<<(n16 + 255) / 256, 256, 0, stream>>>(w32, wp, n16);
  }
  {
    dim3 grid((M / BM) * (N / BN));
    gemm_i8_kernel<<<grid, THREADS, 0, stream>>>(q, wp, atwd, zpws, bias, out, M, N, K);
  }
}